// Round 14
// baseline (115.364 us; speedup 1.0000x reference)
//
#include <hip/hip_runtime.h>
#include <math.h>

#define T_DIM 4096
#define H_DIM 2048
#define N_DIM 1024
#define N2    2048           // 2*N (interleaved re/im) == H
#define KK    2048           // full K of both GEMMs
#define CHUNK 64
#define NCHUNK (T_DIM / CHUNK)
#define NT2   32             // K-tiles: 2048 / 64

using u16    = unsigned short;
using u16x8  = __attribute__((ext_vector_type(8))) u16;
using bf16x8 = __attribute__((ext_vector_type(8))) short;
using f32x4  = __attribute__((ext_vector_type(4))) float;

typedef const __attribute__((address_space(1))) u16 glob_u16;
typedef __attribute__((address_space(3))) u16 lds_u16;

__device__ inline void gload16(const u16* g, u16* l) {
    __builtin_amdgcn_global_load_lds((glob_u16*)g, (lds_u16*)l, 16, 0, 0);
}

__device__ inline u16 f2bf(float x) {   // RNE fp32->bf16
    unsigned u = __builtin_bit_cast(unsigned, x);
    u += 0x7fffu + ((u >> 16) & 1u);
    return (u16)(u >> 16);
}
__device__ inline float bf2f(u16 x) {
    return __builtin_bit_cast(float, (unsigned)x << 16);
}

// Race-proof barrier (R12-verified): lgkmcnt(0) drained BEFORE s_barrier so
// every wave's ds_reads are serviced before anyone can DMA over the buffer.
#define WAIT_BARRIER(N) \
    asm volatile("s_waitcnt vmcnt(" #N ") lgkmcnt(0)\n\ts_barrier" ::: "memory")

// ---------------------------------------------------------------------------
// Merged conversion, grid-stride (2048 blocks, 32B/thread).  INTERLEAVED:
//   Bcat row 2n = gamma*B_re[n], row 2n+1 = gamma*B_im[n]       [2N][H]
//   Ccat[h][2n] = C_re[h][n],   [h][2n+1] = -C_im[h][n]         [H][2N]
// Work units of 2048 elems (256 thr x 8): u<4096 -> U, <6144 -> B, else C.
// ---------------------------------------------------------------------------
__global__ __launch_bounds__(256) void cvt_all_k(
    const float* __restrict__ U, const float* __restrict__ Bre,
    const float* __restrict__ Bim, const float* __restrict__ glog,
    const float* __restrict__ Cre, const float* __restrict__ Cim,
    u16* __restrict__ Ubf, u16* __restrict__ Bcat, u16* __restrict__ Ccat)
{
    for (int u = blockIdx.x; u < 8192; u += 2048) {
        if (u < 4096) {
            size_t i = (size_t)u * 2048 + threadIdx.x * 8;
            float4 v0 = *(const float4*)(U + i);
            float4 v1 = *(const float4*)(U + i + 4);
            u16x8 o = { f2bf(v0.x), f2bf(v0.y), f2bf(v0.z), f2bf(v0.w),
                        f2bf(v1.x), f2bf(v1.y), f2bf(v1.z), f2bf(v1.w) };
            *(u16x8*)(Ubf + i) = o;
        } else if (u < 6144) {
            size_t i = (size_t)(u - 4096) * 2048 + threadIdx.x * 8;
            int rr = (int)(i >> 11);          // row in Bcat [0,2048)
            size_t h = i & 2047;
            int chan = rr >> 1, part = rr & 1;
            float g = expf(glog[chan]);
            const float* src = (part ? Bim : Bre) + (size_t)chan * H_DIM + h;
            float4 v0 = *(const float4*)src;
            float4 v1 = *(const float4*)(src + 4);
            u16x8 o = { f2bf(v0.x * g), f2bf(v0.y * g), f2bf(v0.z * g), f2bf(v0.w * g),
                        f2bf(v1.x * g), f2bf(v1.y * g), f2bf(v1.z * g), f2bf(v1.w * g) };
            *(u16x8*)(Bcat + i) = o;
        } else {
            size_t i = (size_t)(u - 6144) * 2048 + threadIdx.x * 8;
            int hrow = (int)(i >> 11);
            int n2 = (int)(i & 2047);         // multiple of 8 -> 4 complex pairs
            int c0 = n2 >> 1;
            float4 re = *(const float4*)(Cre + (size_t)hrow * N_DIM + c0);
            float4 im = *(const float4*)(Cim + (size_t)hrow * N_DIM + c0);
            u16x8 o = { f2bf(re.x), f2bf(-im.x), f2bf(re.y), f2bf(-im.y),
                        f2bf(re.z), f2bf(-im.z), f2bf(re.w), f2bf(-im.w) };
            *(u16x8*)(Ccat + i) = o;
        }
    }
}

// ---------------------------------------------------------------------------
// gemm_pipe: R8-verified 128^2 kg-split GEMM, full K.  512 thr = 8 waves
// (wr2 x wc2 x kg2), per-wave 64x64 over its K-half; 16 waves/CU.
// LDS = A 3-buf + B 2-buf = 80KB -> 2 blocks/CU.  Race-proof WAIT_BARRIER.
// No setprio (m190: null-to-negative on lockstep GEMM structures).
// kg-merge via LDS (full __syncthreads fences).
// EPI=0: store bf16 Bu; then FUSED CARRY: dump tile to LDS, 128 workers run
//        the 64-step complex scan per (band, channel) -> car2.
// EPI=1: store f32 Y = acc + D[col]*bf2f(Ubf).
// ---------------------------------------------------------------------------
template <int EPI>
__global__ __launch_bounds__(512, 4) void gemm_pipe(
    const u16* __restrict__ A, const u16* __restrict__ B,
    void* __restrict__ Cout, const float* __restrict__ D,
    const u16* __restrict__ Ubf, const float* __restrict__ nu,
    const float* __restrict__ theta, float2* __restrict__ car2)
{
    __shared__ u16 lds[40960];   // A bufs @ 0,8192,16384 ; B bufs @ 24576,32768

    const int tid  = threadIdx.x;
    const int wave = tid >> 6, lane = tid & 63;
    const int nbid = (blockIdx.x & 7) * 64 + (blockIdx.x >> 3);
    const int bm = nbid >> 4;                // 0..31
    const int bn = nbid & 15;                // 0..15
    const size_t row0 = (size_t)bm * 128;
    const size_t col0 = (size_t)bn * 128;
    const int kg = wave & 1;
    const int wc = (wave >> 1) & 1;
    const int wr = wave >> 2;
    const int fr = lane & 15, fq = lane >> 4;

    const int srow = wave * 16 + (lane >> 3);
    const int skc  = (lane & 7) ^ ((lane >> 3) & 7);
    const u16* aSrc = A + (row0 + srow) * KK + skc * 8;
    const u16* bSrc = B + (col0 + srow) * KK + skc * 8;
    const int stOff = wave * 1024;

    const int slot8 = ((kg * 4 + fq) ^ (fr & 7)) * 8;
    const int aOff = (wr * 64 + fr) * 64 + slot8;
    const int bOff = (wc * 64 + fr) * 64 + slot8;

    f32x4 acc[4][4] = {};

    auto STAGE_A = [&](int buf, int kt) {
        gload16(aSrc + kt * 64,          &lds[buf * 8192 + stOff]);
        gload16(aSrc + 8 * KK + kt * 64, &lds[buf * 8192 + stOff + 512]);
    };
    auto STAGE_B = [&](int buf, int kt) {
        gload16(bSrc + kt * 64,          &lds[24576 + buf * 8192 + stOff]);
        gload16(bSrc + 8 * KK + kt * 64, &lds[24576 + buf * 8192 + stOff + 512]);
    };

    bf16x8 fa[4], fb[4];
    auto READ_F = [&](const u16* Ab, const u16* Bb) {
#pragma unroll
        for (int m = 0; m < 4; ++m) fa[m] = *(const bf16x8*)&Ab[aOff + m * 1024];
#pragma unroll
        for (int n = 0; n < 4; ++n) fb[n] = *(const bf16x8*)&Bb[bOff + n * 1024];
    };

    STAGE_A(0, 0); STAGE_B(0, 0); STAGE_A(1, 1);
    WAIT_BARRIER(2);
    READ_F(&lds[0], &lds[24576]);

    int a_cur = 0;
    for (int t = 0; t < NT2; ++t) {
        if (t + 1 < NT2) STAGE_B((t + 1) & 1, t + 1);
#pragma unroll
        for (int m = 0; m < 4; ++m)
#pragma unroll
            for (int n = 0; n < 4; ++n)
                acc[m][n] = __builtin_amdgcn_mfma_f32_16x16x32_bf16(
                    fa[m], fb[n], acc[m][n], 0, 0, 0);
        if (t + 2 < NT2) {
            int a_nxt = a_cur + 2; if (a_nxt >= 3) a_nxt -= 3;
            STAGE_A(a_nxt, t + 2);
        }
        if (t + 1 < NT2) {
            if (t + 2 < NT2) WAIT_BARRIER(2);
            else             WAIT_BARRIER(0);
            int a_n = a_cur + 1; if (a_n == 3) a_n = 0;
            READ_F(&lds[a_n * 8192], &lds[24576 + ((t + 1) & 1) * 8192]);
        }
        ++a_cur; if (a_cur == 3) a_cur = 0;
    }

    // ---- kg-merge via LDS (full fences) ----
    __syncthreads();
    const int pair = wr * 2 + wc;
    float* lf = (float*)lds;
    if (kg == 1) {
#pragma unroll
        for (int i = 0; i < 16; ++i)
            *(f32x4*)&lf[pair * 4096 + i * 256 + lane * 4] = acc[i >> 2][i & 3];
    }
    __syncthreads();
    if (kg == 0) {
#pragma unroll
        for (int i = 0; i < 16; ++i) {
            f32x4 o = *(const f32x4*)&lf[pair * 4096 + i * 256 + lane * 4];
            acc[i >> 2][i & 3] += o;
        }
    }
    const int crow = (int)row0 + wr * 64 + fq * 4;
    const int ccol = (int)col0 + wc * 64 + fr;

    if constexpr (EPI) {
        if (kg == 0) {
            float dc[4];
#pragma unroll
            for (int n = 0; n < 4; ++n) dc[n] = D[ccol + n * 16];
#pragma unroll
            for (int m = 0; m < 4; ++m)
#pragma unroll
                for (int n = 0; n < 4; ++n) {
                    int cc = ccol + n * 16;
#pragma unroll
                    for (int j = 0; j < 4; ++j) {
                        int r = crow + m * 16 + j;
                        size_t p = (size_t)r * N2 + cc;
                        ((float*)Cout)[p] = acc[m][n][j] + dc[n] * bf2f(Ubf[p]);
                    }
                }
        }
    } else {
        // store bf16 Bu to global AND to LDS tile [128][128] for fused carry
        __syncthreads();                       // merge reads done; lds reusable
        u16* tile = lds;                       // 16384 u16 = 32KB
        if (kg == 0) {
#pragma unroll
            for (int m = 0; m < 4; ++m)
#pragma unroll
                for (int n = 0; n < 4; ++n) {
                    int cc = ccol + n * 16;
                    int lc = (wc * 64 + fr) + n * 16;        // col in tile
#pragma unroll
                    for (int j = 0; j < 4; ++j) {
                        int r = crow + m * 16 + j;
                        int lr = (wr * 64 + fq * 4 + j) + m * 16;  // row in tile
                        u16 v = f2bf(acc[m][n][j]);
                        ((u16*)Cout)[(size_t)r * N2 + cc] = v;
                        tile[lr * 128 + lc] = v;
                    }
                }
        }
        __syncthreads();                       // tile complete
        // fused carry: 128 workers = 2 bands x 64 channels
        if (tid < 128) {
            int band = tid >> 6;               // 0..1 (chunk within block)
            int ch   = tid & 63;               // channel within block
            int chan = ((int)col0 >> 1) + ch;  // global channel
            float a = expf(nu[chan]), b = expf(theta[chan]);
            float mm = expf(-a), s, c;
            __sincosf(b, &s, &c);
            float lr_ = mm * c, li_ = mm * s;
            float hr = 0.f, hi = 0.f;
            const u16* rowp = &tile[band * 64 * 128 + 2 * ch];
            for (int i = 0; i < CHUNK; ++i) {
                unsigned pr = *(const unsigned*)(rowp + i * 128);
                float br = bf2f((u16)(pr & 0xffff));
                float bi = bf2f((u16)(pr >> 16));
                float nr = fmaf(lr_, hr, fmaf(-li_, hi, br));
                float ni = fmaf(lr_, hi, fmaf(li_, hr, bi));
                hr = nr; hi = ni;
            }
            int ckG = bm * 2 + band;
            car2[(size_t)ckG * N_DIM + chan] = make_float2(hr, hi);
        }
    }
}

// ---------------------------------------------------------------------------
// pass 2: combine carries across chunks (lambda^CHUNK closed form), float2
// ---------------------------------------------------------------------------
__global__ __launch_bounds__(256) void scan_carry_k(float2* __restrict__ car2,
                                                    const float* __restrict__ nu,
                                                    const float* __restrict__ theta) {
    __shared__ float2 sc[NCHUNK][65];
    int tid = threadIdx.x;
    int chan0 = blockIdx.x * 64;
    for (int i = tid; i < NCHUNK * 64; i += 256) {
        int ck = i >> 6, c = i & 63;
        sc[ck][c] = car2[(size_t)ck * N_DIM + chan0 + c];
    }
    __syncthreads();
    if (tid < 64) {
        int chan = chan0 + tid;
        float a = expf(nu[chan]), b = expf(theta[chan]);
        float m = expf(-(float)CHUNK * a), s, c;
        __sincosf((float)CHUNK * b, &s, &c);
        float lr = m * c, li = m * s;
        float2 h = sc[0][tid];
        for (int ck = 1; ck < NCHUNK; ++ck) {
            float2 v = sc[ck][tid];
            float nr = fmaf(lr, h.x, fmaf(-li, h.y, v.x));
            float ni = fmaf(lr, h.y, fmaf(li, h.x, v.y));
            h.x = nr; h.y = ni;
            sc[ck][tid] = h;
        }
    }
    __syncthreads();
    for (int i = tid; i < NCHUNK * 64; i += 256) {
        int ck = i >> 6, c = i & 63;
        car2[(size_t)ck * N_DIM + chan0 + c] = sc[ck][c];
    }
}

// ---------------------------------------------------------------------------
// pass 3: recompute local scan seeded with combined carry, write bf16 h.
// Interleaved pairs: one u32 load/store per (t, channel).
// ---------------------------------------------------------------------------
__global__ __launch_bounds__(256) void scan_out_k(const u16* __restrict__ Bu,
                                                  const float2* __restrict__ car2,
                                                  const float* __restrict__ nu,
                                                  const float* __restrict__ theta,
                                                  u16* __restrict__ Hbf) {
    int idx = blockIdx.x * 256 + threadIdx.x;   // 0 .. NCHUNK*N-1
    int chan = idx & (N_DIM - 1);
    int chunk = idx >> 10;
    float a = expf(nu[chan]), b = expf(theta[chan]);
    float m = expf(-a), s, c;
    __sincosf(b, &s, &c);
    float lr = m * c, li = m * s;
    float hr = 0.f, hi = 0.f;
    if (chunk > 0) {
        float2 h0 = car2[(size_t)(chunk - 1) * N_DIM + chan];
        hr = h0.x; hi = h0.y;
    }
    size_t base = (size_t)chunk * CHUNK * N2 + 2 * chan;
    for (int i = 0; i < CHUNK; ++i) {
        size_t p = base + (size_t)i * N2;
        unsigned pr = *(const unsigned*)(Bu + p);
        float br = bf2f((u16)(pr & 0xffff));
        float bi = bf2f((u16)(pr >> 16));
        float nr = fmaf(lr, hr, fmaf(-li, hi, br));
        float ni = fmaf(lr, hi, fmaf(li, hr, bi));
        hr = nr; hi = ni;
        *(unsigned*)(Hbf + p) = (unsigned)f2bf(hr) | ((unsigned)f2bf(hi) << 16);
    }
}

extern "C" void kernel_launch(void* const* d_in, const int* in_sizes, int n_in,
                              void* d_out, int out_size, void* d_ws, size_t ws_size,
                              hipStream_t stream) {
    const float* U     = (const float*)d_in[0];
    const float* nu    = (const float*)d_in[1];
    const float* theta = (const float*)d_in[2];
    const float* glog  = (const float*)d_in[3];
    const float* Bre   = (const float*)d_in[4];
    const float* Bim   = (const float*)d_in[5];
    const float* Cre   = (const float*)d_in[6];
    const float* Cim   = (const float*)d_in[7];
    const float* Dp    = (const float*)d_in[8];
    float* Y = (float*)d_out;

    u16* Ubf  = (u16*)d_ws;                             // T*H       bf16 16MB
    u16* Bcat = Ubf + (size_t)T_DIM * H_DIM;            // 2N*H      bf16  8MB
    u16* Ccat = Bcat + (size_t)N2 * H_DIM;              // H*2N      bf16  8MB
    u16* Hbf  = Ccat + (size_t)H_DIM * N2;              // T*2N      bf16 16MB
    u16* Bu   = Hbf + (size_t)T_DIM * N2;               // T*2N      bf16 16MB
    float2* car2 = (float2*)(Bu + (size_t)T_DIM * N2);  // NCHUNK*N  f2  0.5MB

    cvt_all_k<<<2048, 256, 0, stream>>>(U, Bre, Bim, glog, Cre, Cim,
                                        Ubf, Bcat, Ccat);

    gemm_pipe<0><<<512, 512, 0, stream>>>(Ubf, Bcat, (void*)Bu, nullptr,
                                          nullptr, nu, theta, car2);

    scan_carry_k<<<N_DIM / 64, 256, 0, stream>>>(car2, nu, theta);
    scan_out_k<<<(NCHUNK * N_DIM) / 256, 256, 0, stream>>>(Bu, car2, nu, theta, Hbf);

    gemm_pipe<1><<<512, 512, 0, stream>>>(Hbf, Ccat, (void*)Y, Dp,
                                          Ubf, nullptr, nullptr, nullptr);
}

// Round 15
// 113.729 us; speedup vs baseline: 1.0144x; 1.0144x over previous
//
#include <hip/hip_runtime.h>
#include <math.h>

#define T_DIM 4096
#define H_DIM 2048
#define N_DIM 1024
#define N2    2048           // 2*N (interleaved re/im) == H
#define KK    2048           // full K of both GEMMs
#define CHUNK 32
#define NCHUNK (T_DIM / CHUNK)   // 128
#define NT2   32             // K-tiles: 2048 / 64

using u16    = unsigned short;
using u16x4  = __attribute__((ext_vector_type(4))) u16;
using bf16x8 = __attribute__((ext_vector_type(8))) short;
using f32x4  = __attribute__((ext_vector_type(4))) float;

typedef const __attribute__((address_space(1))) u16 glob_u16;
typedef __attribute__((address_space(3))) u16 lds_u16;

__device__ inline void gload16(const u16* g, u16* l) {
    __builtin_amdgcn_global_load_lds((glob_u16*)g, (lds_u16*)l, 16, 0, 0);
}

__device__ inline u16 f2bf(float x) {   // RNE fp32->bf16
    unsigned u = __builtin_bit_cast(unsigned, x);
    u += 0x7fffu + ((u >> 16) & 1u);
    return (u16)(u >> 16);
}
__device__ inline float bf2f(u16 x) {
    return __builtin_bit_cast(float, (unsigned)x << 16);
}

// Race-proof barrier (R12-verified): lgkmcnt(0) drained BEFORE s_barrier so
// every wave's ds_reads are serviced before anyone can DMA over the buffer.
#define WAIT_BARRIER(N) \
    asm volatile("s_waitcnt vmcnt(" #N ") lgkmcnt(0)\n\ts_barrier" ::: "memory")

// ---------------------------------------------------------------------------
// Merged conversion (R13-validated).  INTERLEAVED:
//   Bcat row 2n = gamma*B_re[n], row 2n+1 = gamma*B_im[n]       [2N][H]
//   Ccat[h][2n] = C_re[h][n],   [h][2n+1] = -C_im[h][n]         [H][2N]
// ---------------------------------------------------------------------------
__global__ __launch_bounds__(256) void cvt_all_k(
    const float* __restrict__ U, const float* __restrict__ Bre,
    const float* __restrict__ Bim, const float* __restrict__ glog,
    const float* __restrict__ Cre, const float* __restrict__ Cim,
    u16* __restrict__ Ubf, u16* __restrict__ Bcat, u16* __restrict__ Ccat)
{
    int bid = blockIdx.x;
    if (bid < 8192) {
        size_t i = ((size_t)bid * 256 + threadIdx.x) * 4;
        float4 v = *(const float4*)(U + i);
        u16x4 o = { f2bf(v.x), f2bf(v.y), f2bf(v.z), f2bf(v.w) };
        *(u16x4*)(Ubf + i) = o;
    } else if (bid < 12288) {
        size_t i = ((size_t)(bid - 8192) * 256 + threadIdx.x) * 4;
        int rr = (int)(i >> 11);          // row in Bcat [0,2048)
        size_t h = i & 2047;
        int chan = rr >> 1, part = rr & 1;
        float g = expf(glog[chan]);
        const float* src = (part ? Bim : Bre) + (size_t)chan * H_DIM + h;
        float4 v = *(const float4*)src;
        u16x4 o = { f2bf(v.x * g), f2bf(v.y * g), f2bf(v.z * g), f2bf(v.w * g) };
        *(u16x4*)(Bcat + i) = o;
    } else {
        size_t i = ((size_t)(bid - 12288) * 256 + threadIdx.x) * 4;
        int hrow = (int)(i >> 11);
        int n2 = (int)(i & 2047);         // multiple of 4
        int c0 = n2 >> 1;
        float2 re = *(const float2*)(Cre + (size_t)hrow * N_DIM + c0);
        float2 im = *(const float2*)(Cim + (size_t)hrow * N_DIM + c0);
        u16x4 o = { f2bf(re.x), f2bf(-im.x), f2bf(re.y), f2bf(-im.y) };
        *(u16x4*)(Ccat + i) = o;
    }
}

// ---------------------------------------------------------------------------
// gemm_pipe: R13-validated 128^2 kg-split GEMM, full K.  512 thr = 8 waves
// (wr2 x wc2 x kg2), per-wave 64x64 over its K-half; 16 waves/CU.
// LDS = A 3-buf + B 2-buf = 80KB -> 2 blocks/CU.  Race-proof WAIT_BARRIER.
// kg-merge via LDS (full __syncthreads fences).
// EPI=0: store bf16 Bu; then FUSED CARRY: dump tile to LDS, 256 workers run
//        the 32-step complex scan per (band, channel) -> car2.
// EPI=1: store f32 Y = acc + D[col]*bf2f(Ubf).
// ---------------------------------------------------------------------------
template <int EPI>
__global__ __launch_bounds__(512, 4) void gemm_pipe(
    const u16* __restrict__ A, const u16* __restrict__ B,
    void* __restrict__ Cout, const float* __restrict__ D,
    const u16* __restrict__ Ubf, const float* __restrict__ nu,
    const float* __restrict__ theta, float2* __restrict__ car2)
{
    __shared__ u16 lds[40960];   // A bufs @ 0,8192,16384 ; B bufs @ 24576,32768

    const int tid  = threadIdx.x;
    const int wave = tid >> 6, lane = tid & 63;
    const int nbid = (blockIdx.x & 7) * 64 + (blockIdx.x >> 3);
    const int bm = nbid >> 4;                // 0..31
    const int bn = nbid & 15;                // 0..15
    const size_t row0 = (size_t)bm * 128;
    const size_t col0 = (size_t)bn * 128;
    const int kg = wave & 1;
    const int wc = (wave >> 1) & 1;
    const int wr = wave >> 2;
    const int fr = lane & 15, fq = lane >> 4;

    const int srow = wave * 16 + (lane >> 3);
    const int skc  = (lane & 7) ^ ((lane >> 3) & 7);
    const u16* aSrc = A + (row0 + srow) * KK + skc * 8;
    const u16* bSrc = B + (col0 + srow) * KK + skc * 8;
    const int stOff = wave * 1024;

    const int slot8 = ((kg * 4 + fq) ^ (fr & 7)) * 8;
    const int aOff = (wr * 64 + fr) * 64 + slot8;
    const int bOff = (wc * 64 + fr) * 64 + slot8;

    f32x4 acc[4][4] = {};

    auto STAGE_A = [&](int buf, int kt) {
        gload16(aSrc + kt * 64,          &lds[buf * 8192 + stOff]);
        gload16(aSrc + 8 * KK + kt * 64, &lds[buf * 8192 + stOff + 512]);
    };
    auto STAGE_B = [&](int buf, int kt) {
        gload16(bSrc + kt * 64,          &lds[24576 + buf * 8192 + stOff]);
        gload16(bSrc + 8 * KK + kt * 64, &lds[24576 + buf * 8192 + stOff + 512]);
    };

    bf16x8 fa[4], fb[4];
    auto READ_F = [&](const u16* Ab, const u16* Bb) {
#pragma unroll
        for (int m = 0; m < 4; ++m) fa[m] = *(const bf16x8*)&Ab[aOff + m * 1024];
#pragma unroll
        for (int n = 0; n < 4; ++n) fb[n] = *(const bf16x8*)&Bb[bOff + n * 1024];
    };

    STAGE_A(0, 0); STAGE_B(0, 0); STAGE_A(1, 1);
    WAIT_BARRIER(2);
    READ_F(&lds[0], &lds[24576]);

    int a_cur = 0;
    for (int t = 0; t < NT2; ++t) {
        if (t + 1 < NT2) STAGE_B((t + 1) & 1, t + 1);
        __builtin_amdgcn_s_setprio(1);
#pragma unroll
        for (int m = 0; m < 4; ++m)
#pragma unroll
            for (int n = 0; n < 4; ++n)
                acc[m][n] = __builtin_amdgcn_mfma_f32_16x16x32_bf16(
                    fa[m], fb[n], acc[m][n], 0, 0, 0);
        __builtin_amdgcn_s_setprio(0);
        if (t + 2 < NT2) {
            int a_nxt = a_cur + 2; if (a_nxt >= 3) a_nxt -= 3;
            STAGE_A(a_nxt, t + 2);
        }
        if (t + 1 < NT2) {
            if (t + 2 < NT2) WAIT_BARRIER(2);
            else             WAIT_BARRIER(0);
            int a_n = a_cur + 1; if (a_n == 3) a_n = 0;
            READ_F(&lds[a_n * 8192], &lds[24576 + ((t + 1) & 1) * 8192]);
        }
        ++a_cur; if (a_cur == 3) a_cur = 0;
    }

    // ---- kg-merge via LDS (full fences) ----
    __syncthreads();
    const int pair = wr * 2 + wc;
    float* lf = (float*)lds;
    if (kg == 1) {
#pragma unroll
        for (int i = 0; i < 16; ++i)
            *(f32x4*)&lf[pair * 4096 + i * 256 + lane * 4] = acc[i >> 2][i & 3];
    }
    __syncthreads();
    if (kg == 0) {
#pragma unroll
        for (int i = 0; i < 16; ++i) {
            f32x4 o = *(const f32x4*)&lf[pair * 4096 + i * 256 + lane * 4];
            acc[i >> 2][i & 3] += o;
        }
    }
    const int crow = (int)row0 + wr * 64 + fq * 4;
    const int ccol = (int)col0 + wc * 64 + fr;

    if constexpr (EPI) {
        if (kg == 0) {
            float dc[4];
#pragma unroll
            for (int n = 0; n < 4; ++n) dc[n] = D[ccol + n * 16];
#pragma unroll
            for (int m = 0; m < 4; ++m)
#pragma unroll
                for (int n = 0; n < 4; ++n) {
                    int cc = ccol + n * 16;
#pragma unroll
                    for (int j = 0; j < 4; ++j) {
                        int r = crow + m * 16 + j;
                        size_t p = (size_t)r * N2 + cc;
                        ((float*)Cout)[p] = acc[m][n][j] + dc[n] * bf2f(Ubf[p]);
                    }
                }
        }
    } else {
        // store bf16 Bu to global AND to LDS tile [128][128] for fused carry
        __syncthreads();                       // merge reads done; lds reusable
        u16* tile = lds;                       // 16384 u16 = 32KB
        if (kg == 0) {
#pragma unroll
            for (int m = 0; m < 4; ++m)
#pragma unroll
                for (int n = 0; n < 4; ++n) {
                    int cc = ccol + n * 16;
                    int lc = (wc * 64 + fr) + n * 16;        // col in tile
#pragma unroll
                    for (int j = 0; j < 4; ++j) {
                        int r = crow + m * 16 + j;
                        int lr = (wr * 64 + fq * 4 + j) + m * 16;  // row in tile
                        u16 v = f2bf(acc[m][n][j]);
                        ((u16*)Cout)[(size_t)r * N2 + cc] = v;
                        tile[lr * 128 + lc] = v;
                    }
                }
        }
        __syncthreads();                       // tile complete
        // fused carry: 256 workers = 4 bands (32 rows each) x 64 channels
        if (tid < 256) {
            int band = tid >> 6;               // 0..3 (chunk within block)
            int ch   = tid & 63;               // channel within block
            int chan = ((int)col0 >> 1) + ch;  // global channel
            float a = expf(nu[chan]), b = expf(theta[chan]);
            float mm = expf(-a), s, c;
            __sincosf(b, &s, &c);
            float lr_ = mm * c, li_ = mm * s;
            float hr = 0.f, hi = 0.f;
            const u16* rowp = &tile[band * CHUNK * 128 + 2 * ch];
            for (int i = 0; i < CHUNK; ++i) {
                unsigned pr = *(const unsigned*)(rowp + i * 128);
                float br = bf2f((u16)(pr & 0xffff));
                float bi = bf2f((u16)(pr >> 16));
                float nr = fmaf(lr_, hr, fmaf(-li_, hi, br));
                float ni = fmaf(lr_, hi, fmaf(li_, hr, bi));
                hr = nr; hi = ni;
            }
            int ckG = bm * 4 + band;
            car2[(size_t)ckG * N_DIM + chan] = make_float2(hr, hi);
        }
    }
}

// ---------------------------------------------------------------------------
// pass 2: combine carries across chunks (lambda^CHUNK closed form), float2
// ---------------------------------------------------------------------------
__global__ __launch_bounds__(256) void scan_carry_k(float2* __restrict__ car2,
                                                    const float* __restrict__ nu,
                                                    const float* __restrict__ theta) {
    __shared__ float2 sc[NCHUNK][65];
    int tid = threadIdx.x;
    int chan0 = blockIdx.x * 64;
    for (int i = tid; i < NCHUNK * 64; i += 256) {
        int ck = i >> 6, c = i & 63;
        sc[ck][c] = car2[(size_t)ck * N_DIM + chan0 + c];
    }
    __syncthreads();
    if (tid < 64) {
        int chan = chan0 + tid;
        float a = expf(nu[chan]), b = expf(theta[chan]);
        float m = expf(-(float)CHUNK * a), s, c;
        __sincosf((float)CHUNK * b, &s, &c);
        float lr = m * c, li = m * s;
        float2 h = sc[0][tid];
        for (int ck = 1; ck < NCHUNK; ++ck) {
            float2 v = sc[ck][tid];
            float nr = fmaf(lr, h.x, fmaf(-li, h.y, v.x));
            float ni = fmaf(lr, h.y, fmaf(li, h.x, v.y));
            h.x = nr; h.y = ni;
            sc[ck][tid] = h;
        }
    }
    __syncthreads();
    for (int i = tid; i < NCHUNK * 64; i += 256) {
        int ck = i >> 6, c = i & 63;
        car2[(size_t)ck * N_DIM + chan0 + c] = sc[ck][c];
    }
}

// ---------------------------------------------------------------------------
// pass 3: recompute local scan seeded with combined carry, write bf16 h.
// CHUNK=32 -> 512 blocks (2/CU): doubles occupancy, halves the serial chain.
// ---------------------------------------------------------------------------
__global__ __launch_bounds__(256) void scan_out_k(const u16* __restrict__ Bu,
                                                  const float2* __restrict__ car2,
                                                  const float* __restrict__ nu,
                                                  const float* __restrict__ theta,
                                                  u16* __restrict__ Hbf) {
    int idx = blockIdx.x * 256 + threadIdx.x;   // 0 .. NCHUNK*N-1
    int chan = idx & (N_DIM - 1);
    int chunk = idx >> 10;
    float a = expf(nu[chan]), b = expf(theta[chan]);
    float m = expf(-a), s, c;
    __sincosf(b, &s, &c);
    float lr = m * c, li = m * s;
    float hr = 0.f, hi = 0.f;
    if (chunk > 0) {
        float2 h0 = car2[(size_t)(chunk - 1) * N_DIM + chan];
        hr = h0.x; hi = h0.y;
    }
    size_t base = (size_t)chunk * CHUNK * N2 + 2 * chan;
    for (int i = 0; i < CHUNK; ++i) {
        size_t p = base + (size_t)i * N2;
        unsigned pr = *(const unsigned*)(Bu + p);
        float br = bf2f((u16)(pr & 0xffff));
        float bi = bf2f((u16)(pr >> 16));
        float nr = fmaf(lr, hr, fmaf(-li, hi, br));
        float ni = fmaf(lr, hi, fmaf(li, hr, bi));
        hr = nr; hi = ni;
        *(unsigned*)(Hbf + p) = (unsigned)f2bf(hr) | ((unsigned)f2bf(hi) << 16);
    }
}

extern "C" void kernel_launch(void* const* d_in, const int* in_sizes, int n_in,
                              void* d_out, int out_size, void* d_ws, size_t ws_size,
                              hipStream_t stream) {
    const float* U     = (const float*)d_in[0];
    const float* nu    = (const float*)d_in[1];
    const float* theta = (const float*)d_in[2];
    const float* glog  = (const float*)d_in[3];
    const float* Bre   = (const float*)d_in[4];
    const float* Bim   = (const float*)d_in[5];
    const float* Cre   = (const float*)d_in[6];
    const float* Cim   = (const float*)d_in[7];
    const float* Dp    = (const float*)d_in[8];
    float* Y = (float*)d_out;

    u16* Ubf  = (u16*)d_ws;                             // T*H       bf16 16MB
    u16* Bcat = Ubf + (size_t)T_DIM * H_DIM;            // 2N*H      bf16  8MB
    u16* Ccat = Bcat + (size_t)N2 * H_DIM;              // H*2N      bf16  8MB
    u16* Hbf  = Ccat + (size_t)H_DIM * N2;              // T*2N      bf16 16MB
    u16* Bu   = Hbf + (size_t)T_DIM * N2;               // T*2N      bf16 16MB
    float2* car2 = (float2*)(Bu + (size_t)T_DIM * N2);  // NCHUNK*N  f2   1MB

    cvt_all_k<<<16384, 256, 0, stream>>>(U, Bre, Bim, glog, Cre, Cim,
                                         Ubf, Bcat, Ccat);

    gemm_pipe<0><<<512, 512, 0, stream>>>(Ubf, Bcat, (void*)Bu, nullptr,
                                          nullptr, nu, theta, car2);

    scan_carry_k<<<N_DIM / 64, 256, 0, stream>>>(car2, nu, theta);
    scan_out_k<<<(NCHUNK * N_DIM) / 256, 256, 0, stream>>>(Bu, car2, nu, theta, Hbf);

    gemm_pipe<1><<<512, 512, 0, stream>>>(Hbf, Ccat, (void*)Y, Dp,
                                          Ubf, nullptr, nullptr, nullptr);
}

// Round 16
// 113.037 us; speedup vs baseline: 1.0206x; 1.0061x over previous
//
#include <hip/hip_runtime.h>
#include <math.h>

#define T_DIM 4096
#define H_DIM 2048
#define N_DIM 1024
#define N2    2048           // 2*N (interleaved re/im) == H
#define KK    2048           // full K of both GEMMs
#define CHUNK 64
#define NCHUNK (T_DIM / CHUNK)
#define NT2   32             // K-tiles: 2048 / 64

using u16    = unsigned short;
using u16x4  = __attribute__((ext_vector_type(4))) u16;
using bf16x8 = __attribute__((ext_vector_type(8))) short;
using f32x4  = __attribute__((ext_vector_type(4))) float;

typedef const __attribute__((address_space(1))) u16 glob_u16;
typedef __attribute__((address_space(3))) u16 lds_u16;

__device__ inline void gload16(const u16* g, u16* l) {
    __builtin_amdgcn_global_load_lds((glob_u16*)g, (lds_u16*)l, 16, 0, 0);
}

__device__ inline u16 f2bf(float x) {   // RNE fp32->bf16
    unsigned u = __builtin_bit_cast(unsigned, x);
    u += 0x7fffu + ((u >> 16) & 1u);
    return (u16)(u >> 16);
}
__device__ inline float bf2f(u16 x) {
    return __builtin_bit_cast(float, (unsigned)x << 16);
}

// Race-proof barrier (R12-verified): lgkmcnt(0) drained BEFORE s_barrier so
// every wave's ds_reads are serviced before anyone can DMA over the buffer.
#define WAIT_BARRIER(N) \
    asm volatile("s_waitcnt vmcnt(" #N ") lgkmcnt(0)\n\ts_barrier" ::: "memory")

// ---------------------------------------------------------------------------
// Merged conversion.  INTERLEAVED layouts:
//   Bcat row 2n = gamma*B_re[n], row 2n+1 = gamma*B_im[n]       [2N][H]
//   Ccat[h][2n] = C_re[h][n],   [h][2n+1] = -C_im[h][n]         [H][2N]
// ---------------------------------------------------------------------------
__global__ __launch_bounds__(256) void cvt_all_k(
    const float* __restrict__ U, const float* __restrict__ Bre,
    const float* __restrict__ Bim, const float* __restrict__ glog,
    const float* __restrict__ Cre, const float* __restrict__ Cim,
    u16* __restrict__ Ubf, u16* __restrict__ Bcat, u16* __restrict__ Ccat)
{
    int bid = blockIdx.x;
    if (bid < 8192) {
        size_t i = ((size_t)bid * 256 + threadIdx.x) * 4;
        float4 v = *(const float4*)(U + i);
        u16x4 o = { f2bf(v.x), f2bf(v.y), f2bf(v.z), f2bf(v.w) };
        *(u16x4*)(Ubf + i) = o;
    } else if (bid < 12288) {
        size_t i = ((size_t)(bid - 8192) * 256 + threadIdx.x) * 4;
        int rr = (int)(i >> 11);          // row in Bcat [0,2048)
        size_t h = i & 2047;
        int chan = rr >> 1, part = rr & 1;
        float g = expf(glog[chan]);
        const float* src = (part ? Bim : Bre) + (size_t)chan * H_DIM + h;
        float4 v = *(const float4*)src;
        u16x4 o = { f2bf(v.x * g), f2bf(v.y * g), f2bf(v.z * g), f2bf(v.w * g) };
        *(u16x4*)(Bcat + i) = o;
    } else {
        size_t i = ((size_t)(bid - 12288) * 256 + threadIdx.x) * 4;
        int hrow = (int)(i >> 11);
        int n2 = (int)(i & 2047);         // multiple of 4
        int c0 = n2 >> 1;
        float2 re = *(const float2*)(Cre + (size_t)hrow * N_DIM + c0);
        float2 im = *(const float2*)(Cim + (size_t)hrow * N_DIM + c0);
        u16x4 o = { f2bf(re.x), f2bf(-im.x), f2bf(re.y), f2bf(-im.y) };
        *(u16x4*)(Ccat + i) = o;
    }
}

// ---------------------------------------------------------------------------
// gemm_pipe: R13-validated 128^2 kg-split GEMM, full K.  512 thr = 8 waves
// (wr2 x wc2 x kg2), per-wave 64x64 over its K-half; 16 waves/CU.
// LDS = A 3-buf + B 2-buf = 80KB -> 2 blocks/CU.  Race-proof WAIT_BARRIER.
// kg-merge via LDS (full __syncthreads fences).
// EPI=0: store bf16 Bu; then FUSED CARRY: dump tile to LDS, 128 workers run
//        the 64-step complex scan per (band, channel) -> car2.
// EPI=1: store f32 Y = acc + D[col]*bf2f(Ubf).
// ---------------------------------------------------------------------------
template <int EPI>
__global__ __launch_bounds__(512, 4) void gemm_pipe(
    const u16* __restrict__ A, const u16* __restrict__ B,
    void* __restrict__ Cout, const float* __restrict__ D,
    const u16* __restrict__ Ubf, const float* __restrict__ nu,
    const float* __restrict__ theta, float2* __restrict__ car2)
{
    __shared__ u16 lds[40960];   // A bufs @ 0,8192,16384 ; B bufs @ 24576,32768

    const int tid  = threadIdx.x;
    const int wave = tid >> 6, lane = tid & 63;
    const int nbid = (blockIdx.x & 7) * 64 + (blockIdx.x >> 3);
    const int bm = nbid >> 4;                // 0..31
    const int bn = nbid & 15;                // 0..15
    const size_t row0 = (size_t)bm * 128;
    const size_t col0 = (size_t)bn * 128;
    const int kg = wave & 1;
    const int wc = (wave >> 1) & 1;
    const int wr = wave >> 2;
    const int fr = lane & 15, fq = lane >> 4;

    const int srow = wave * 16 + (lane >> 3);
    const int skc  = (lane & 7) ^ ((lane >> 3) & 7);
    const u16* aSrc = A + (row0 + srow) * KK + skc * 8;
    const u16* bSrc = B + (col0 + srow) * KK + skc * 8;
    const int stOff = wave * 1024;

    const int slot8 = ((kg * 4 + fq) ^ (fr & 7)) * 8;
    const int aOff = (wr * 64 + fr) * 64 + slot8;
    const int bOff = (wc * 64 + fr) * 64 + slot8;

    f32x4 acc[4][4] = {};

    auto STAGE_A = [&](int buf, int kt) {
        gload16(aSrc + kt * 64,          &lds[buf * 8192 + stOff]);
        gload16(aSrc + 8 * KK + kt * 64, &lds[buf * 8192 + stOff + 512]);
    };
    auto STAGE_B = [&](int buf, int kt) {
        gload16(bSrc + kt * 64,          &lds[24576 + buf * 8192 + stOff]);
        gload16(bSrc + 8 * KK + kt * 64, &lds[24576 + buf * 8192 + stOff + 512]);
    };

    bf16x8 fa[4], fb[4];
    auto READ_F = [&](const u16* Ab, const u16* Bb) {
#pragma unroll
        for (int m = 0; m < 4; ++m) fa[m] = *(const bf16x8*)&Ab[aOff + m * 1024];
#pragma unroll
        for (int n = 0; n < 4; ++n) fb[n] = *(const bf16x8*)&Bb[bOff + n * 1024];
    };

    STAGE_A(0, 0); STAGE_B(0, 0); STAGE_A(1, 1);
    WAIT_BARRIER(2);
    READ_F(&lds[0], &lds[24576]);

    int a_cur = 0;
    for (int t = 0; t < NT2; ++t) {
        if (t + 1 < NT2) STAGE_B((t + 1) & 1, t + 1);
        __builtin_amdgcn_s_setprio(1);
#pragma unroll
        for (int m = 0; m < 4; ++m)
#pragma unroll
            for (int n = 0; n < 4; ++n)
                acc[m][n] = __builtin_amdgcn_mfma_f32_16x16x32_bf16(
                    fa[m], fb[n], acc[m][n], 0, 0, 0);
        __builtin_amdgcn_s_setprio(0);
        if (t + 2 < NT2) {
            int a_nxt = a_cur + 2; if (a_nxt >= 3) a_nxt -= 3;
            STAGE_A(a_nxt, t + 2);
        }
        if (t + 1 < NT2) {
            if (t + 2 < NT2) WAIT_BARRIER(2);
            else             WAIT_BARRIER(0);
            int a_n = a_cur + 1; if (a_n == 3) a_n = 0;
            READ_F(&lds[a_n * 8192], &lds[24576 + ((t + 1) & 1) * 8192]);
        }
        ++a_cur; if (a_cur == 3) a_cur = 0;
    }

    // ---- kg-merge via LDS (full fences) ----
    __syncthreads();
    const int pair = wr * 2 + wc;
    float* lf = (float*)lds;
    if (kg == 1) {
#pragma unroll
        for (int i = 0; i < 16; ++i)
            *(f32x4*)&lf[pair * 4096 + i * 256 + lane * 4] = acc[i >> 2][i & 3];
    }
    __syncthreads();
    if (kg == 0) {
#pragma unroll
        for (int i = 0; i < 16; ++i) {
            f32x4 o = *(const f32x4*)&lf[pair * 4096 + i * 256 + lane * 4];
            acc[i >> 2][i & 3] += o;
        }
    }
    const int crow = (int)row0 + wr * 64 + fq * 4;
    const int ccol = (int)col0 + wc * 64 + fr;

    if constexpr (EPI) {
        if (kg == 0) {
            float dc[4];
#pragma unroll
            for (int n = 0; n < 4; ++n) dc[n] = D[ccol + n * 16];
#pragma unroll
            for (int m = 0; m < 4; ++m)
#pragma unroll
                for (int n = 0; n < 4; ++n) {
                    int cc = ccol + n * 16;
#pragma unroll
                    for (int j = 0; j < 4; ++j) {
                        int r = crow + m * 16 + j;
                        size_t p = (size_t)r * N2 + cc;
                        ((float*)Cout)[p] = acc[m][n][j] + dc[n] * bf2f(Ubf[p]);
                    }
                }
        }
    } else {
        // store bf16 Bu to global AND to LDS tile [128][128] for fused carry
        __syncthreads();                       // merge reads done; lds reusable
        u16* tile = lds;                       // 16384 u16 = 32KB
        if (kg == 0) {
#pragma unroll
            for (int m = 0; m < 4; ++m)
#pragma unroll
                for (int n = 0; n < 4; ++n) {
                    int cc = ccol + n * 16;
                    int lc = (wc * 64 + fr) + n * 16;        // col in tile
#pragma unroll
                    for (int j = 0; j < 4; ++j) {
                        int r = crow + m * 16 + j;
                        int lr = (wr * 64 + fq * 4 + j) + m * 16;  // row in tile
                        u16 v = f2bf(acc[m][n][j]);
                        ((u16*)Cout)[(size_t)r * N2 + cc] = v;
                        tile[lr * 128 + lc] = v;
                    }
                }
        }
        __syncthreads();                       // tile complete
        // fused carry: 128 workers = 2 bands x 64 channels
        if (tid < 128) {
            int band = tid >> 6;               // 0..1 (chunk within block)
            int ch   = tid & 63;               // channel within block
            int chan = ((int)col0 >> 1) + ch;  // global channel
            float a = expf(nu[chan]), b = expf(theta[chan]);
            float mm = expf(-a), s, c;
            __sincosf(b, &s, &c);
            float lr_ = mm * c, li_ = mm * s;
            float hr = 0.f, hi = 0.f;
            const u16* rowp = &tile[band * 64 * 128 + 2 * ch];
            for (int i = 0; i < CHUNK; ++i) {
                unsigned pr = *(const unsigned*)(rowp + i * 128);
                float br = bf2f((u16)(pr & 0xffff));
                float bi = bf2f((u16)(pr >> 16));
                float nr = fmaf(lr_, hr, fmaf(-li_, hi, br));
                float ni = fmaf(lr_, hi, fmaf(li_, hr, bi));
                hr = nr; hi = ni;
            }
            int ckG = bm * 2 + band;
            car2[(size_t)ckG * N_DIM + chan] = make_float2(hr, hi);
        }
    }
}

// ---------------------------------------------------------------------------
// pass 2: combine carries across chunks (lambda^CHUNK closed form), float2
// ---------------------------------------------------------------------------
__global__ __launch_bounds__(256) void scan_carry_k(float2* __restrict__ car2,
                                                    const float* __restrict__ nu,
                                                    const float* __restrict__ theta) {
    __shared__ float2 sc[NCHUNK][65];
    int tid = threadIdx.x;
    int chan0 = blockIdx.x * 64;
    for (int i = tid; i < NCHUNK * 64; i += 256) {
        int ck = i >> 6, c = i & 63;
        sc[ck][c] = car2[(size_t)ck * N_DIM + chan0 + c];
    }
    __syncthreads();
    if (tid < 64) {
        int chan = chan0 + tid;
        float a = expf(nu[chan]), b = expf(theta[chan]);
        float m = expf(-(float)CHUNK * a), s, c;
        __sincosf((float)CHUNK * b, &s, &c);
        float lr = m * c, li = m * s;
        float2 h = sc[0][tid];
        for (int ck = 1; ck < NCHUNK; ++ck) {
            float2 v = sc[ck][tid];
            float nr = fmaf(lr, h.x, fmaf(-li, h.y, v.x));
            float ni = fmaf(lr, h.y, fmaf(li, h.x, v.y));
            h.x = nr; h.y = ni;
            sc[ck][tid] = h;
        }
    }
    __syncthreads();
    for (int i = tid; i < NCHUNK * 64; i += 256) {
        int ck = i >> 6, c = i & 63;
        car2[(size_t)ck * N_DIM + chan0 + c] = sc[ck][c];
    }
}

// ---------------------------------------------------------------------------
// pass 3: recompute local scan seeded with combined carry, write bf16 h.
// Interleaved pairs: one u32 load/store per (t, channel).
// ---------------------------------------------------------------------------
__global__ __launch_bounds__(256) void scan_out_k(const u16* __restrict__ Bu,
                                                  const float2* __restrict__ car2,
                                                  const float* __restrict__ nu,
                                                  const float* __restrict__ theta,
                                                  u16* __restrict__ Hbf) {
    int idx = blockIdx.x * 256 + threadIdx.x;   // 0 .. NCHUNK*N-1
    int chan = idx & (N_DIM - 1);
    int chunk = idx >> 10;
    float a = expf(nu[chan]), b = expf(theta[chan]);
    float m = expf(-a), s, c;
    __sincosf(b, &s, &c);
    float lr = m * c, li = m * s;
    float hr = 0.f, hi = 0.f;
    if (chunk > 0) {
        float2 h0 = car2[(size_t)(chunk - 1) * N_DIM + chan];
        hr = h0.x; hi = h0.y;
    }
    size_t base = (size_t)chunk * CHUNK * N2 + 2 * chan;
    for (int i = 0; i < CHUNK; ++i) {
        size_t p = base + (size_t)i * N2;
        unsigned pr = *(const unsigned*)(Bu + p);
        float br = bf2f((u16)(pr & 0xffff));
        float bi = bf2f((u16)(pr >> 16));
        float nr = fmaf(lr, hr, fmaf(-li, hi, br));
        float ni = fmaf(lr, hi, fmaf(li, hr, bi));
        hr = nr; hi = ni;
        *(unsigned*)(Hbf + p) = (unsigned)f2bf(hr) | ((unsigned)f2bf(hi) << 16);
    }
}

extern "C" void kernel_launch(void* const* d_in, const int* in_sizes, int n_in,
                              void* d_out, int out_size, void* d_ws, size_t ws_size,
                              hipStream_t stream) {
    const float* U     = (const float*)d_in[0];
    const float* nu    = (const float*)d_in[1];
    const float* theta = (const float*)d_in[2];
    const float* glog  = (const float*)d_in[3];
    const float* Bre   = (const float*)d_in[4];
    const float* Bim   = (const float*)d_in[5];
    const float* Cre   = (const float*)d_in[6];
    const float* Cim   = (const float*)d_in[7];
    const float* Dp    = (const float*)d_in[8];
    float* Y = (float*)d_out;

    u16* Ubf  = (u16*)d_ws;                             // T*H       bf16 16MB
    u16* Bcat = Ubf + (size_t)T_DIM * H_DIM;            // 2N*H      bf16  8MB
    u16* Ccat = Bcat + (size_t)N2 * H_DIM;              // H*2N      bf16  8MB
    u16* Hbf  = Ccat + (size_t)H_DIM * N2;              // T*2N      bf16 16MB
    u16* Bu   = Hbf + (size_t)T_DIM * N2;               // T*2N      bf16 16MB
    float2* car2 = (float2*)(Bu + (size_t)T_DIM * N2);  // NCHUNK*N  f2  0.5MB

    cvt_all_k<<<16384, 256, 0, stream>>>(U, Bre, Bim, glog, Cre, Cim,
                                         Ubf, Bcat, Ccat);

    gemm_pipe<0><<<512, 512, 0, stream>>>(Ubf, Bcat, (void*)Bu, nullptr,
                                          nullptr, nu, theta, car2);

    scan_carry_k<<<N_DIM / 64, 256, 0, stream>>>(car2, nu, theta);
    scan_out_k<<<(NCHUNK * N_DIM) / 256, 256, 0, stream>>>(Bu, car2, nu, theta, Hbf);

    gemm_pipe<1><<<512, 512, 0, stream>>>(Hbf, Ccat, (void*)Y, Dp,
                                          Ubf, nullptr, nullptr, nullptr);
}